// Round 6
// baseline (207.230 us; speedup 1.0000x reference)
//
#include <hip/hip_runtime.h>
#include <cstdint>

#define NSTARS 4096
#define NDIC   4096
#define NFEAT  16
#define NPIX   65536    // 256*256
#define BATCH  2048
#define BPB    128      // batch rows per k_opd block

using f32x4 = __attribute__((ext_vector_type(4))) float;

// ---------------------------------------------------------------------------
// Kernel A v3: fused lookup + inter, high-occupancy.
// 512 blocks x 1024 threads (16 waves). Wave w owns (row = w>>2, seg = w&3):
// acc[16]/thread, alpha read exactly once per block (256KB -> 128MiB L2
// total), segment partials combined in LDS (no global partial traffic),
// lookup once per 4 rows. vs R2: 2x waves/CU, 4x smaller accumulator.
// ---------------------------------------------------------------------------
__global__ __launch_bounds__(1024) void k_inter(
    const float*  __restrict__ positions,   // [BATCH,2]
    const float2* __restrict__ obs,         // [NSTARS] as float2
    const float*  __restrict__ spatial,     // [NSTARS,NDIC]
    const float*  __restrict__ alpha,       // [NDIC,NFEAT]
    float*        __restrict__ inter)       // [BATCH,NFEAT] out
{
    __shared__ int   s_idx[4];
    __shared__ float s_red[16 * NFEAT];     // [wave][feat]

    const int tid  = threadIdx.x;
    const int lane = tid & 63;
    const int wave = tid >> 6;              // 0..15
    const int b0   = blockIdx.x * 4;

    if (tid < 4) s_idx[tid] = 0x7FFFFFFF;
    __syncthreads();

    // lookup: first flat-equal element row-major -> min star with x OR y match
    float px[4], py[4];
    #pragma unroll
    for (int b = 0; b < 4; ++b) {
        px[b] = positions[(b0 + b) * 2 + 0];
        py[b] = positions[(b0 + b) * 2 + 1];
    }
    for (int s = tid; s < NSTARS; s += 1024) {   // 4 iters
        float2 o = obs[s];
        #pragma unroll
        for (int b = 0; b < 4; ++b) {
            if (px[b] == o.x || py[b] == o.y) atomicMin(&s_idx[b], s);
        }
    }
    __syncthreads();

    const int rloc = wave >> 2;             // local row 0..3
    const int seg  = wave & 3;              // d-segment 0..3 (1024 wide)
    const int v    = s_idx[rloc];
    const int idx  = (v == 0x7FFFFFFF) ? 0 : v;

    const float*  srow   = spatial + (size_t)idx * NDIC + seg * 1024;
    const float4* alpha4 = (const float4*)alpha;

    float acc[NFEAT];
    #pragma unroll
    for (int f = 0; f < NFEAT; ++f) acc[f] = 0.0f;

    #pragma unroll
    for (int pass = 0; pass < 4; ++pass) {
        const int d  = pass * 256 + lane * 4;    // [0,1024) within segment
        const int gd = seg * 1024 + d;           // global d
        const float4 vv = *(const float4*)(srow + d);
        #pragma unroll
        for (int k = 0; k < 4; ++k) {
            const float4 a0 = alpha4[(size_t)(gd + k) * 4 + 0];
            const float4 a1 = alpha4[(size_t)(gd + k) * 4 + 1];
            const float4 a2 = alpha4[(size_t)(gd + k) * 4 + 2];
            const float4 a3 = alpha4[(size_t)(gd + k) * 4 + 3];
            const float vb = (&vv.x)[k];
            acc[0]  += vb * a0.x;  acc[1]  += vb * a0.y;
            acc[2]  += vb * a0.z;  acc[3]  += vb * a0.w;
            acc[4]  += vb * a1.x;  acc[5]  += vb * a1.y;
            acc[6]  += vb * a1.z;  acc[7]  += vb * a1.w;
            acc[8]  += vb * a2.x;  acc[9]  += vb * a2.y;
            acc[10] += vb * a2.z;  acc[11] += vb * a2.w;
            acc[12] += vb * a3.x;  acc[13] += vb * a3.y;
            acc[14] += vb * a3.z;  acc[15] += vb * a3.w;
        }
    }

    // 64-lane butterfly: 6 levels x 16 feats
    #pragma unroll
    for (int off = 1; off < 64; off <<= 1)
        #pragma unroll
        for (int f = 0; f < NFEAT; ++f)
            acc[f] += __shfl_xor(acc[f], off);

    if (lane == 0) {
        #pragma unroll
        for (int f = 0; f < NFEAT; f += 4)
            *(float4*)&s_red[wave * NFEAT + f] =
                make_float4(acc[f], acc[f+1], acc[f+2], acc[f+3]);
    }
    __syncthreads();

    if (tid < 64) {
        const int r = tid >> 4, f = tid & 15;
        const float x = s_red[(r * 4 + 0) * NFEAT + f]
                      + s_red[(r * 4 + 1) * NFEAT + f]
                      + s_red[(r * 4 + 2) * NFEAT + f]
                      + s_red[(r * 4 + 3) * NFEAT + f];
        inter[(size_t)(b0 + r) * NFEAT + f] = x;
    }
}

// ---------------------------------------------------------------------------
// Kernel B: exact R2 (control). nt stores, BPB=128.
// ---------------------------------------------------------------------------
__global__ __launch_bounds__(256) void k_opd(
    const float4* __restrict__ inter4,  // [BATCH, 4] float4 rows
    const f32x4*  __restrict__ S4,      // [NFEAT, NPIX/4]
    f32x4*        __restrict__ out4)    // [BATCH, NPIX/4]
{
    const int tid   = threadIdx.x;
    const int chunk = blockIdx.x & 63;       // pixel chunk (1024 px)
    const int bg    = blockIdx.x >> 6;       // batch group of BPB rows
    const int p4    = chunk * 256 + tid;     // float4 index in [0, 16384)

    f32x4 s[NFEAT];
    #pragma unroll
    for (int f = 0; f < NFEAT; ++f)
        s[f] = S4[(size_t)f * (NPIX / 4) + p4];

    const float4* w4 = inter4 + (size_t)bg * BPB * 4;
    f32x4* o = out4 + (size_t)bg * BPB * (NPIX / 4) + p4;

    #pragma unroll 2
    for (int b = 0; b < BPB; ++b) {
        const float4 wa = w4[b * 4 + 0];
        const float4 wb = w4[b * 4 + 1];
        const float4 wc = w4[b * 4 + 2];
        const float4 wd = w4[b * 4 + 3];

        f32x4 acc = s[0] * wa.x;
        acc += s[1]  * wa.y;  acc += s[2]  * wa.z;  acc += s[3]  * wa.w;
        acc += s[4]  * wb.x;  acc += s[5]  * wb.y;  acc += s[6]  * wb.z;
        acc += s[7]  * wb.w;  acc += s[8]  * wc.x;  acc += s[9]  * wc.y;
        acc += s[10] * wc.z;  acc += s[11] * wc.w;  acc += s[12] * wd.x;
        acc += s[13] * wd.y;  acc += s[14] * wd.z;  acc += s[15] * wd.w;

        __builtin_nontemporal_store(acc, o + (size_t)b * (NPIX / 4));
    }
}

extern "C" void kernel_launch(void* const* d_in, const int* in_sizes, int n_in,
                              void* d_out, int out_size, void* d_ws, size_t ws_size,
                              hipStream_t stream) {
    const float*  positions = (const float*)d_in[0];   // [2048,2]
    const float2* obs       = (const float2*)d_in[1];  // [4096,2]
    const float*  spatial   = (const float*)d_in[2];   // [4096,4096]
    const float*  alpha     = (const float*)d_in[3];   // [4096,16]
    const f32x4*  S4        = (const f32x4*)d_in[4];   // [16,256,256]
    f32x4*        out       = (f32x4*)d_out;           // [2048,256,256]
    float*        inter     = (float*)d_ws;            // [2048,16] scratch

    k_inter<<<BATCH / 4, 1024, 0, stream>>>(positions, obs, spatial, alpha, inter);
    k_opd<<<(NPIX / 1024) * (BATCH / BPB), 256, 0, stream>>>(
        (const float4*)inter, S4, out);
}

// Round 7
// 146.762 us; speedup vs baseline: 1.4120x; 1.4120x over previous
//
#include <hip/hip_runtime.h>
#include <cstdint>

#define NSTARS 4096
#define NDIC   4096
#define NFEAT  16
#define NPIX   65536    // 256*256
#define BATCH  2048
#define BPB    128      // batch rows per k_opd block

using f32x4 = __attribute__((ext_vector_type(4))) float;

// ---------------------------------------------------------------------------
// Kernel A: exact R2 k_inter (control; ~32us, VMEM-issue-bound on alpha).
// 512 blocks x 256 threads, 4 rows/block share each alpha load (FMA:VMEM=256:20).
// ---------------------------------------------------------------------------
__global__ __launch_bounds__(256) void k_inter(
    const float*  __restrict__ positions,   // [BATCH,2]
    const float2* __restrict__ obs,         // [NSTARS] as float2
    const float*  __restrict__ spatial,     // [NSTARS,NDIC]
    const float*  __restrict__ alpha,       // [NDIC,NFEAT]
    float*        __restrict__ inter)       // [BATCH,NFEAT] out
{
    __shared__ int   s_idx[4];
    __shared__ float s_red[4 * 64];

    const int tid = threadIdx.x;
    const int b0  = blockIdx.x * 4;

    if (tid < 4) s_idx[tid] = 0x7FFFFFFF;
    __syncthreads();

    float px[4], py[4];
    #pragma unroll
    for (int b = 0; b < 4; ++b) {
        px[b] = positions[(b0 + b) * 2 + 0];
        py[b] = positions[(b0 + b) * 2 + 1];
    }

    for (int s = tid; s < NSTARS; s += 256) {
        float2 o = obs[s];
        #pragma unroll
        for (int b = 0; b < 4; ++b) {
            if (px[b] == o.x || py[b] == o.y) atomicMin(&s_idx[b], s);
        }
    }
    __syncthreads();

    int idx[4];
    #pragma unroll
    for (int b = 0; b < 4; ++b) {
        int v = s_idx[b];
        idx[b] = (v == 0x7FFFFFFF) ? 0 : v;
    }

    float acc[4][NFEAT];
    #pragma unroll
    for (int b = 0; b < 4; ++b)
        #pragma unroll
        for (int f = 0; f < NFEAT; ++f) acc[b][f] = 0.0f;

    const float4* alpha4 = (const float4*)alpha;

    #pragma unroll
    for (int step = 0; step < 4; ++step) {
        const int d0 = tid * 4 + step * 1024;
        float4 v[4];
        #pragma unroll
        for (int b = 0; b < 4; ++b)
            v[b] = *(const float4*)(spatial + (size_t)idx[b] * NDIC + d0);

        #pragma unroll
        for (int k = 0; k < 4; ++k) {
            const float4 a0 = alpha4[(size_t)(d0 + k) * 4 + 0];
            const float4 a1 = alpha4[(size_t)(d0 + k) * 4 + 1];
            const float4 a2 = alpha4[(size_t)(d0 + k) * 4 + 2];
            const float4 a3 = alpha4[(size_t)(d0 + k) * 4 + 3];
            #pragma unroll
            for (int b = 0; b < 4; ++b) {
                const float vb = (&v[b].x)[k];
                acc[b][0]  += vb * a0.x;  acc[b][1]  += vb * a0.y;
                acc[b][2]  += vb * a0.z;  acc[b][3]  += vb * a0.w;
                acc[b][4]  += vb * a1.x;  acc[b][5]  += vb * a1.y;
                acc[b][6]  += vb * a1.z;  acc[b][7]  += vb * a1.w;
                acc[b][8]  += vb * a2.x;  acc[b][9]  += vb * a2.y;
                acc[b][10] += vb * a2.z;  acc[b][11] += vb * a2.w;
                acc[b][12] += vb * a3.x;  acc[b][13] += vb * a3.y;
                acc[b][14] += vb * a3.z;  acc[b][15] += vb * a3.w;
            }
        }
    }

    #pragma unroll
    for (int b = 0; b < 4; ++b)
        #pragma unroll
        for (int f = 0; f < NFEAT; ++f) {
            float x = acc[b][f];
            #pragma unroll
            for (int off = 32; off > 0; off >>= 1)
                x += __shfl_down(x, off);
            acc[b][f] = x;
        }

    const int lane = tid & 63;
    const int wave = tid >> 6;
    if (lane == 0) {
        #pragma unroll
        for (int b = 0; b < 4; ++b)
            #pragma unroll
            for (int f = 0; f < NFEAT; ++f)
                s_red[wave * 64 + b * NFEAT + f] = acc[b][f];
    }
    __syncthreads();

    if (tid < 64) {
        const int b = tid >> 4, f = tid & 15;
        float x = s_red[0 * 64 + tid] + s_red[1 * 64 + tid]
                + s_red[2 * 64 + tid] + s_red[3 * 64 + tid];
        inter[(size_t)(b0 + b) * NFEAT + f] = x;
    }
}

// ---------------------------------------------------------------------------
// Kernel B v3: 4-row groups -> 4 independent FMA chains (ILP) + burst of 4
// nt stores per group. Single change vs R2's unroll-2 sequential pattern.
// ---------------------------------------------------------------------------
__global__ __launch_bounds__(256) void k_opd(
    const float4* __restrict__ inter4,  // [BATCH, 4] float4 rows
    const f32x4*  __restrict__ S4,      // [NFEAT, NPIX/4]
    f32x4*        __restrict__ out4)    // [BATCH, NPIX/4]
{
    const int tid   = threadIdx.x;
    const int chunk = blockIdx.x & 63;       // pixel chunk (1024 px)
    const int bg    = blockIdx.x >> 6;       // batch group of BPB rows
    const int p4    = chunk * 256 + tid;     // float4 index in [0, 16384)

    f32x4 s[NFEAT];
    #pragma unroll
    for (int f = 0; f < NFEAT; ++f)
        s[f] = S4[(size_t)f * (NPIX / 4) + p4];

    const float4* w4 = inter4 + (size_t)bg * BPB * 4;
    f32x4* o = out4 + (size_t)bg * BPB * (NPIX / 4) + p4;

    for (int g = 0; g < BPB / 4; ++g) {
        f32x4 acc[4];
        // 4 independent chains; row b+1's w-loads overlap row b's FMA chain.
        #pragma unroll
        for (int b = 0; b < 4; ++b) {
            const int r = g * 4 + b;
            const float4 wa = w4[r * 4 + 0];
            const float4 wb = w4[r * 4 + 1];
            const float4 wc = w4[r * 4 + 2];
            const float4 wd = w4[r * 4 + 3];
            f32x4 a = s[0] * wa.x;
            a += s[1]  * wa.y;  a += s[2]  * wa.z;  a += s[3]  * wa.w;
            a += s[4]  * wb.x;  a += s[5]  * wb.y;  a += s[6]  * wb.z;
            a += s[7]  * wb.w;  a += s[8]  * wc.x;  a += s[9]  * wc.y;
            a += s[10] * wc.z;  a += s[11] * wc.w;  a += s[12] * wd.x;
            a += s[13] * wd.y;  a += s[14] * wd.z;  a += s[15] * wd.w;
            acc[b] = a;
        }
        // burst the 4 stores back-to-back
        #pragma unroll
        for (int b = 0; b < 4; ++b)
            __builtin_nontemporal_store(acc[b],
                o + (size_t)(g * 4 + b) * (NPIX / 4));
    }
}

extern "C" void kernel_launch(void* const* d_in, const int* in_sizes, int n_in,
                              void* d_out, int out_size, void* d_ws, size_t ws_size,
                              hipStream_t stream) {
    const float*  positions = (const float*)d_in[0];   // [2048,2]
    const float2* obs       = (const float2*)d_in[1];  // [4096,2]
    const float*  spatial   = (const float*)d_in[2];   // [4096,4096]
    const float*  alpha     = (const float*)d_in[3];   // [4096,16]
    const f32x4*  S4        = (const f32x4*)d_in[4];   // [16,256,256]
    f32x4*        out       = (f32x4*)d_out;           // [2048,256,256]
    float*        inter     = (float*)d_ws;            // [2048,16] scratch

    k_inter<<<BATCH / 4, 256, 0, stream>>>(positions, obs, spatial, alpha, inter);
    k_opd<<<(NPIX / 1024) * (BATCH / BPB), 256, 0, stream>>>(
        (const float4*)inter, S4, out);
}

// Round 8
// 131.945 us; speedup vs baseline: 1.5706x; 1.1123x over previous
//
#include <hip/hip_runtime.h>
#include <cstdint>

#define NSTARS 4096
#define NDIC   4096
#define NFEAT  16
#define NPIX   65536    // 256*256
#define BATCH  2048
#define RPB    8        // rows per k_inter block
#define BPB    256      // batch rows per k_opd block

using f32x4 = __attribute__((ext_vector_type(4))) float;

// ---------------------------------------------------------------------------
// Kernel A v4: 8 rows/block halves alpha VMEM instruction count
// (10.5M -> 6.3M total; k_inter is VMEM-issue bound per R6 evidence).
// 256 blocks x 256 threads; acc[8][16] = 128 VGPR -> ~2 waves/SIMD.
// ---------------------------------------------------------------------------
__global__ __launch_bounds__(256) void k_inter(
    const float*  __restrict__ positions,   // [BATCH,2]
    const float2* __restrict__ obs,         // [NSTARS] as float2
    const float*  __restrict__ spatial,     // [NSTARS,NDIC]
    const float*  __restrict__ alpha,       // [NDIC,NFEAT]
    float*        __restrict__ inter)       // [BATCH,NFEAT] out
{
    __shared__ int   s_idx[RPB];
    __shared__ float s_red[4 * RPB * NFEAT];   // [wave][row][feat]

    const int tid  = threadIdx.x;
    const int lane = tid & 63;
    const int wave = tid >> 6;
    const int b0   = blockIdx.x * RPB;

    if (tid < RPB) s_idx[tid] = 0x7FFFFFFF;
    __syncthreads();

    // lookup: first flat-equal element row-major -> min star with x OR y match
    float px[RPB], py[RPB];
    #pragma unroll
    for (int b = 0; b < RPB; ++b) {
        px[b] = positions[(b0 + b) * 2 + 0];
        py[b] = positions[(b0 + b) * 2 + 1];
    }
    for (int s = tid; s < NSTARS; s += 256) {
        float2 o = obs[s];
        #pragma unroll
        for (int b = 0; b < RPB; ++b) {
            if (px[b] == o.x || py[b] == o.y) atomicMin(&s_idx[b], s);
        }
    }
    __syncthreads();

    int idx[RPB];
    #pragma unroll
    for (int b = 0; b < RPB; ++b) {
        int v = s_idx[b];
        idx[b] = (v == 0x7FFFFFFF) ? 0 : v;
    }

    float acc[RPB][NFEAT];
    #pragma unroll
    for (int b = 0; b < RPB; ++b)
        #pragma unroll
        for (int f = 0; f < NFEAT; ++f) acc[b][f] = 0.0f;

    const float4* alpha4 = (const float4*)alpha;

    #pragma unroll
    for (int step = 0; step < 4; ++step) {
        const int d0 = tid * 4 + step * 1024;
        float4 v[RPB];
        #pragma unroll
        for (int b = 0; b < RPB; ++b)
            v[b] = *(const float4*)(spatial + (size_t)idx[b] * NDIC + d0);

        #pragma unroll
        for (int k = 0; k < 4; ++k) {
            const float4 a0 = alpha4[(size_t)(d0 + k) * 4 + 0];
            const float4 a1 = alpha4[(size_t)(d0 + k) * 4 + 1];
            const float4 a2 = alpha4[(size_t)(d0 + k) * 4 + 2];
            const float4 a3 = alpha4[(size_t)(d0 + k) * 4 + 3];
            #pragma unroll
            for (int b = 0; b < RPB; ++b) {
                const float vb = (&v[b].x)[k];
                acc[b][0]  += vb * a0.x;  acc[b][1]  += vb * a0.y;
                acc[b][2]  += vb * a0.z;  acc[b][3]  += vb * a0.w;
                acc[b][4]  += vb * a1.x;  acc[b][5]  += vb * a1.y;
                acc[b][6]  += vb * a1.z;  acc[b][7]  += vb * a1.w;
                acc[b][8]  += vb * a2.x;  acc[b][9]  += vb * a2.y;
                acc[b][10] += vb * a2.z;  acc[b][11] += vb * a2.w;
                acc[b][12] += vb * a3.x;  acc[b][13] += vb * a3.y;
                acc[b][14] += vb * a3.z;  acc[b][15] += vb * a3.w;
            }
        }
    }

    // 64-lane butterfly over 128 (row,feat) values
    #pragma unroll
    for (int off = 1; off < 64; off <<= 1)
        #pragma unroll
        for (int b = 0; b < RPB; ++b)
            #pragma unroll
            for (int f = 0; f < NFEAT; ++f)
                acc[b][f] += __shfl_xor(acc[b][f], off);

    if (lane == 0) {
        #pragma unroll
        for (int b = 0; b < RPB; ++b)
            #pragma unroll
            for (int f = 0; f < NFEAT; f += 4)
                *(float4*)&s_red[(wave * RPB + b) * NFEAT + f] =
                    make_float4(acc[b][f], acc[b][f+1], acc[b][f+2], acc[b][f+3]);
    }
    __syncthreads();

    if (tid < RPB * NFEAT) {            // 128 threads
        const int r = tid >> 4, f = tid & 15;
        float x = s_red[(0 * RPB + r) * NFEAT + f]
                + s_red[(1 * RPB + r) * NFEAT + f]
                + s_red[(2 * RPB + r) * NFEAT + f]
                + s_red[(3 * RPB + r) * NFEAT + f];
        inter[(size_t)(b0 + r) * NFEAT + f] = x;
    }
}

// ---------------------------------------------------------------------------
// Kernel B v4: BPB=256 (S re-fetch 64->32 MiB) + block-uniform scalar w-loads
// (s_load on scalar pipe; SGPR operand feeds v_fma directly; removes the
// 256x-redundant per-lane VMEM w reads). nt store burst kept from R7.
// Grid: 64 chunks x 8 bg = 512 blocks.
// ---------------------------------------------------------------------------
__global__ __launch_bounds__(256) void k_opd(
    const float* __restrict__ interw,   // [BATCH, NFEAT]
    const f32x4* __restrict__ S4,       // [NFEAT, NPIX/4]
    f32x4*       __restrict__ out4)     // [BATCH, NPIX/4]
{
    const int tid   = threadIdx.x;
    const int chunk = blockIdx.x & 63;       // pixel chunk (1024 px)
    const int bg    = blockIdx.x >> 6;       // batch group of BPB rows (0..7)
    const int p4    = chunk * 256 + tid;     // float4 index in [0, 16384)

    f32x4 s[NFEAT];
    #pragma unroll
    for (int f = 0; f < NFEAT; ++f)
        s[f] = S4[(size_t)f * (NPIX / 4) + p4];

    const float* w = interw + (size_t)bg * BPB * NFEAT;   // block-uniform
    f32x4* o = out4 + (size_t)bg * BPB * (NPIX / 4) + p4;

    for (int g = 0; g < BPB / 4; ++g) {
        f32x4 acc[4];
        #pragma unroll
        for (int b = 0; b < 4; ++b) {
            const float* wr = w + (size_t)(g * 4 + b) * NFEAT;  // uniform addr
            f32x4 a = s[0] * wr[0];
            a += s[1]  * wr[1];   a += s[2]  * wr[2];   a += s[3]  * wr[3];
            a += s[4]  * wr[4];   a += s[5]  * wr[5];   a += s[6]  * wr[6];
            a += s[7]  * wr[7];   a += s[8]  * wr[8];   a += s[9]  * wr[9];
            a += s[10] * wr[10];  a += s[11] * wr[11];  a += s[12] * wr[12];
            a += s[13] * wr[13];  a += s[14] * wr[14];  a += s[15] * wr[15];
            acc[b] = a;
        }
        #pragma unroll
        for (int b = 0; b < 4; ++b)
            __builtin_nontemporal_store(acc[b],
                o + (size_t)(g * 4 + b) * (NPIX / 4));
    }
}

extern "C" void kernel_launch(void* const* d_in, const int* in_sizes, int n_in,
                              void* d_out, int out_size, void* d_ws, size_t ws_size,
                              hipStream_t stream) {
    const float*  positions = (const float*)d_in[0];   // [2048,2]
    const float2* obs       = (const float2*)d_in[1];  // [4096,2]
    const float*  spatial   = (const float*)d_in[2];   // [4096,4096]
    const float*  alpha     = (const float*)d_in[3];   // [4096,16]
    const f32x4*  S4        = (const f32x4*)d_in[4];   // [16,256,256]
    f32x4*        out       = (f32x4*)d_out;           // [2048,256,256]
    float*        inter     = (float*)d_ws;            // [2048,16] scratch

    k_inter<<<BATCH / RPB, 256, 0, stream>>>(positions, obs, spatial, alpha, inter);
    k_opd<<<(NPIX / 1024) * (BATCH / BPB), 256, 0, stream>>>(
        inter, S4, out);
}